// Round 6
// baseline (28.313 us; speedup 1.0000x reference)
//
#include <hip/hip_runtime.h>
#include <math.h>

// Tiny MLP: 6 -> 8 (relu) -> 4 (relu) -> 2 (relu) -> 1, then softplus.
// R1: native __expf/__logf transcendentals (kept).
// R6: fix per-instruction coalescing. R1's direct loads had 96 B lane
//     stride inside each global_load_dwordx4 (1 KB useful / 6 KB span).
//     Now each wave stages its 6 KB tile into LDS with 6x
//     global_load_lds_dwordx4 at unit lane stride (1 KB/instr, each line
//     touched once), then threads read their 96 B from LDS.

typedef float v4f __attribute__((ext_vector_type(4)));

#define AS1 __attribute__((address_space(1)))
#define AS3 __attribute__((address_space(3)))

__device__ __forceinline__ float softplus_fast(float z) {
    float e = __expf(-fabsf(z));
    return fmaxf(z, 0.0f) + __logf(1.0f + e);
}

__device__ __forceinline__ v4f compute_quad(
    const v4f b[6],
    const float* __restrict__ W1, const float* __restrict__ b1,
    const float* __restrict__ W7, const float* __restrict__ b7,
    const float* __restrict__ W8, const float* __restrict__ b8,
    const float* __restrict__ W9, const float* __restrict__ b9)
{
    float xr[4][6];
    xr[0][0]=b[0].x; xr[0][1]=b[0].y; xr[0][2]=b[0].z; xr[0][3]=b[0].w; xr[0][4]=b[1].x; xr[0][5]=b[1].y;
    xr[1][0]=b[1].z; xr[1][1]=b[1].w; xr[1][2]=b[2].x; xr[1][3]=b[2].y; xr[1][4]=b[2].z; xr[1][5]=b[2].w;
    xr[2][0]=b[3].x; xr[2][1]=b[3].y; xr[2][2]=b[3].z; xr[2][3]=b[3].w; xr[2][4]=b[4].x; xr[2][5]=b[4].y;
    xr[3][0]=b[4].z; xr[3][1]=b[4].w; xr[3][2]=b[5].x; xr[3][3]=b[5].y; xr[3][4]=b[5].z; xr[3][5]=b[5].w;

    float out4[4];
    #pragma unroll
    for (int r = 0; r < 4; ++r) {
        float h1[8];
        #pragma unroll
        for (int j = 0; j < 8; ++j) {
            float acc = b1[j];
            #pragma unroll
            for (int k = 0; k < 6; ++k) acc = fmaf(W1[j * 6 + k], xr[r][k], acc);
            h1[j] = fmaxf(acc, 0.0f);
        }
        float h7[4];
        #pragma unroll
        for (int j = 0; j < 4; ++j) {
            float acc = b7[j];
            #pragma unroll
            for (int k = 0; k < 8; ++k) acc = fmaf(W7[j * 8 + k], h1[k], acc);
            h7[j] = fmaxf(acc, 0.0f);
        }
        float h8[2];
        #pragma unroll
        for (int j = 0; j < 2; ++j) {
            float acc = b8[j];
            #pragma unroll
            for (int k = 0; k < 4; ++k) acc = fmaf(W8[j * 4 + k], h7[k], acc);
            h8[j] = fmaxf(acc, 0.0f);
        }
        float z = fmaf(W9[0], h8[0], fmaf(W9[1], h8[1], b9[0]));
        out4[r] = softplus_fast(z);
    }
    v4f res; res.x = out4[0]; res.y = out4[1]; res.z = out4[2]; res.w = out4[3];
    return res;
}

__global__ __launch_bounds__(256) void encoder_mlp_kernel(
    const float* __restrict__ x,
    const float* __restrict__ W1, const float* __restrict__ b1,
    const float* __restrict__ W7, const float* __restrict__ b7,
    const float* __restrict__ W8, const float* __restrict__ b8,
    const float* __restrict__ W9, const float* __restrict__ b9,
    float* __restrict__ out, int n_quads)
{
    __shared__ v4f lds[4 * 384];            // 4 waves x 6 KB = 24 KB

    const int tid  = threadIdx.x;
    const int wave = tid >> 6;
    const int lane = tid & 63;

    const int t = blockIdx.x * 256 + tid;   // quad index owned by this thread
    const size_t wave_tile = ((size_t)blockIdx.x * 4 + wave) * 384; // float4 units
    const size_t n_f4 = (size_t)n_quads * 6;

    const v4f* x4 = reinterpret_cast<const v4f*>(x);
    v4f* out4 = reinterpret_cast<v4f*>(out);

    const bool full_tile = (wave_tile + 384 <= n_f4);   // wave-uniform

    v4f r[6];
    bool have_quad = ((size_t)t < (size_t)n_quads);

    if (full_tile) {
        v4f* ldsw = &lds[wave * 384];
        #pragma unroll
        for (int j = 0; j < 6; ++j) {
            const v4f* gp = x4 + wave_tile + (size_t)j * 64 + lane;
            __builtin_amdgcn_global_load_lds(
                (AS1 const unsigned int*)gp,
                (AS3 unsigned int*)(ldsw + j * 64),
                16, 0, 0);
        }
        asm volatile("s_waitcnt vmcnt(0)" ::: "memory");
        __builtin_amdgcn_sched_barrier(0);
        const v4f* my = &ldsw[lane * 6];
        r[0] = my[0]; r[1] = my[1]; r[2] = my[2];
        r[3] = my[3]; r[4] = my[4]; r[5] = my[5];
    } else if (have_quad) {
        // tail fallback (unreachable at this problem size): masked scalar loads
        const long long row0 = (long long)t * 4;
        float tmp[24];
        #pragma unroll
        for (int q = 0; q < 4; ++q) {
            long long row = row0 + q;
            #pragma unroll
            for (int k = 0; k < 6; ++k)
                tmp[q * 6 + k] = (row * 6 + k < (long long)n_quads * 24)
                                     ? x[row * 6 + k] : 0.0f;
        }
        #pragma unroll
        for (int j = 0; j < 6; ++j) {
            r[j].x = tmp[j*4+0]; r[j].y = tmp[j*4+1];
            r[j].z = tmp[j*4+2]; r[j].w = tmp[j*4+3];
        }
    }

    if (have_quad)
        out4[t] = compute_quad(r, W1, b1, W7, b7, W8, b8, W9, b9);
}

extern "C" void kernel_launch(void* const* d_in, const int* in_sizes, int n_in,
                              void* d_out, int out_size, void* d_ws, size_t ws_size,
                              hipStream_t stream) {
    const float* x  = (const float*)d_in[0];
    const float* W1 = (const float*)d_in[1];
    const float* b1 = (const float*)d_in[2];
    const float* W7 = (const float*)d_in[3];
    const float* b7 = (const float*)d_in[4];
    const float* W8 = (const float*)d_in[5];
    const float* b8 = (const float*)d_in[6];
    const float* W9 = (const float*)d_in[7];
    const float* b9 = (const float*)d_in[8];
    float* out = (float*)d_out;

    const int n_rows  = in_sizes[0] / 6;     // 4194304
    const int n_quads = (n_rows + 3) / 4;    // 1048576
    const int block = 256;
    const int grid = (n_quads + block - 1) / block;   // 4096 blocks

    encoder_mlp_kernel<<<grid, block, 0, stream>>>(
        x, W1, b1, W7, b7, W8, b8, W9, b9, out, n_quads);
}

// Round 9
// 24.679 us; speedup vs baseline: 1.1473x; 1.1473x over previous
//
#include <hip/hip_runtime.h>
#include <math.h>

// Tiny MLP: 6 -> 8 (relu) -> 4 (relu) -> 2 (relu) -> 1, then softplus.
// FINAL (= R1, best measured 24.69 us): 4 rows/thread, 6x float4 coalesced
// loads, float4 store, native __expf/__logf transcendentals.
//
// Measured model (validated over 6 experiments): dur = ~18.6 us memory floor
// + VALU issue time (~6.2 us at ~117 slots/row). Attempted and rejected:
//  - v_pk_fma_f32 j-packing w/ op_sel broadcast: WRONG RESULTS on gfx950 (R7)
//  - row-pair packing w/ duplicated SGPR weight pairs: needs 160-210 SGPRs,
//    exceeds the ~104 SGPR/wave file
//  - C-level <2 x float> packing: compiler scalarizes + shuffle movs (+2.3 us, R2)
//  - software pipelining / fewer blocks: TLP loss (+3.5 us, R4)
//  - LDS-staged unit-stride loads: vmcnt drain + occupancy (+3.6 us, R5)
//  - bf16-split MFMA: relayout + cvt cost exceeds K=6 matmul savings
// No v_pk_max_f32 exists on gfx950; softplus already lowers to the minimal
// modifier-folded v_mul/v_exp/v_add/v_log/v_fma/v_max sequence.

__device__ __forceinline__ float softplus_fast(float z) {
    // stable: max(z,0) + log(1 + exp(-|z|)), native transcendentals
    float e = __expf(-fabsf(z));            // v_exp_f32 path
    return fmaxf(z, 0.0f) + __logf(1.0f + e); // v_log_f32 path
}

__global__ __launch_bounds__(256) void encoder_mlp_kernel(
    const float* __restrict__ x,
    const float* __restrict__ W1, const float* __restrict__ b1,
    const float* __restrict__ W7, const float* __restrict__ b7,
    const float* __restrict__ W8, const float* __restrict__ b8,
    const float* __restrict__ W9, const float* __restrict__ b9,
    float* __restrict__ out, int n_rows)
{
    const int t = blockIdx.x * blockDim.x + threadIdx.x;
    const long long row0 = (long long)t * 4;
    if (row0 >= n_rows) return;

    float xr[4][6];
    bool full_quad = (row0 + 4 <= n_rows);

    if (full_quad) {
        // 4 rows = 24 floats = 6 x float4, 16B-aligned (t*96 bytes).
        const float4* xin = reinterpret_cast<const float4*>(x) + (size_t)t * 6;
        float4 v0 = xin[0], v1 = xin[1], v2 = xin[2],
               v3 = xin[3], v4 = xin[4], v5 = xin[5];
        xr[0][0] = v0.x; xr[0][1] = v0.y; xr[0][2] = v0.z; xr[0][3] = v0.w; xr[0][4] = v1.x; xr[0][5] = v1.y;
        xr[1][0] = v1.z; xr[1][1] = v1.w; xr[1][2] = v2.x; xr[1][3] = v2.y; xr[1][4] = v2.z; xr[1][5] = v2.w;
        xr[2][0] = v3.x; xr[2][1] = v3.y; xr[2][2] = v3.z; xr[2][3] = v3.w; xr[2][4] = v4.x; xr[2][5] = v4.y;
        xr[3][0] = v4.z; xr[3][1] = v4.w; xr[3][2] = v5.x; xr[3][3] = v5.y; xr[3][4] = v5.z; xr[3][5] = v5.w;
    } else {
        #pragma unroll
        for (int r = 0; r < 4; ++r) {
            long long row = row0 + r;
            #pragma unroll
            for (int k = 0; k < 6; ++k)
                xr[r][k] = (row < n_rows) ? x[row * 6 + k] : 0.0f;
        }
    }

    float res[4];
    #pragma unroll
    for (int r = 0; r < 4; ++r) {
        // layer 1: 6 -> 8, relu
        float h1[8];
        #pragma unroll
        for (int j = 0; j < 8; ++j) {
            float acc = b1[j];
            #pragma unroll
            for (int k = 0; k < 6; ++k) acc = fmaf(W1[j * 6 + k], xr[r][k], acc);
            h1[j] = fmaxf(acc, 0.0f);
        }
        // layer 7: 8 -> 4, relu
        float h7[4];
        #pragma unroll
        for (int j = 0; j < 4; ++j) {
            float acc = b7[j];
            #pragma unroll
            for (int k = 0; k < 8; ++k) acc = fmaf(W7[j * 8 + k], h1[k], acc);
            h7[j] = fmaxf(acc, 0.0f);
        }
        // layer 8: 4 -> 2, relu
        float h8[2];
        #pragma unroll
        for (int j = 0; j < 2; ++j) {
            float acc = b8[j];
            #pragma unroll
            for (int k = 0; k < 4; ++k) acc = fmaf(W8[j * 4 + k], h7[k], acc);
            h8[j] = fmaxf(acc, 0.0f);
        }
        // layer 9: 2 -> 1, softplus
        float z = fmaf(W9[0], h8[0], fmaf(W9[1], h8[1], b9[0]));
        res[r] = softplus_fast(z);
    }

    if (full_quad) {
        float4 o;
        o.x = res[0]; o.y = res[1]; o.z = res[2]; o.w = res[3];
        reinterpret_cast<float4*>(out)[t] = o;
    } else {
        #pragma unroll
        for (int r = 0; r < 4; ++r) {
            long long row = row0 + r;
            if (row < n_rows) out[row] = res[r];
        }
    }
}

extern "C" void kernel_launch(void* const* d_in, const int* in_sizes, int n_in,
                              void* d_out, int out_size, void* d_ws, size_t ws_size,
                              hipStream_t stream) {
    const float* x  = (const float*)d_in[0];
    const float* W1 = (const float*)d_in[1];
    const float* b1 = (const float*)d_in[2];
    const float* W7 = (const float*)d_in[3];
    const float* b7 = (const float*)d_in[4];
    const float* W8 = (const float*)d_in[5];
    const float* b8 = (const float*)d_in[6];
    const float* W9 = (const float*)d_in[7];
    const float* b9 = (const float*)d_in[8];
    float* out = (float*)d_out;

    const int n_rows = in_sizes[0] / 6;               // 4194304
    const int n_threads = (n_rows + 3) / 4;           // 4 rows per thread
    const int block = 256;
    const int grid = (n_threads + block - 1) / block; // 4096 blocks

    encoder_mlp_kernel<<<grid, block, 0, stream>>>(
        x, W1, b1, W7, b7, W8, b8, W9, b9, out, n_rows);
}